// Round 1
// baseline (587.200 us; speedup 1.0000x reference)
//
#include <hip/hip_runtime.h>
#include <stdint.h>

// Problem constants (B=1024, Y=50000, inputs: input_ f32[B*Y], target f32[B*Y],
// max_num_trials i32[1]; output: f32[1] = sum of per-row WARP losses).
#define BN 1024
#define YN 50000

// ---------------- Threefry-2x32, key (0, 42) --------------------------------
// JAX partitionable path: element i (flat, row-major) gets
//   (o0, o1) = threefry2x32(k1=0, k2=42, x0 = i>>32 (=0 here), x1 = i&0xffffffff)
//   bits = o0 ^ o1
// uniform = bitcast((bits>>9) | 0x3f800000) - 1  -> ordering is monotone in
// (bits>>9), so we use (bits>>9, col) as the u64 sort key (stable-sort tiebreak
// by column index matches jnp.argsort stable=True).

#define TF_ROUND(r) { x0 += x1; x1 = (x1 << (r)) | (x1 >> (32 - (r))); x1 ^= x0; }

__device__ __forceinline__ uint32_t tf_bits(uint32_t ctr) {
    const uint32_t ks0 = 0u;
    const uint32_t ks1 = 42u;
    const uint32_t ks2 = 0x1BD11BDAu ^ 0u ^ 42u;
    uint32_t x0 = ks0;        // hi counter (0) + ks0
    uint32_t x1 = ctr + ks1;  // lo counter + ks1
    TF_ROUND(13) TF_ROUND(15) TF_ROUND(26) TF_ROUND(6)
    x0 += ks1; x1 += ks2 + 1u;
    TF_ROUND(17) TF_ROUND(29) TF_ROUND(16) TF_ROUND(24)
    x0 += ks2; x1 += ks0 + 2u;
    TF_ROUND(13) TF_ROUND(15) TF_ROUND(26) TF_ROUND(6)
    x0 += ks0; x1 += ks1 + 3u;
    TF_ROUND(17) TF_ROUND(29) TF_ROUND(16) TF_ROUND(24)
    x0 += ks1; x1 += ks2 + 4u;
    TF_ROUND(13) TF_ROUND(15) TF_ROUND(26) TF_ROUND(6)
    x0 += ks2; x1 += ks0 + 5u;
    return x0 ^ x1;
}

__device__ __forceinline__ uint64_t sort_key(uint32_t bits, int col) {
    return ((uint64_t)(bits >> 9) << 32) | (uint32_t)col;
}

// ---------------- Kernel 1: find pos + pos_score per row --------------------
__global__ __launch_bounds__(256) void find_pos_kernel(
    const float* __restrict__ target, const float* __restrict__ input,
    int* __restrict__ ws_pos, float* __restrict__ ws_ps)
{
    const int row = blockIdx.x;
    const size_t base = (size_t)row * YN;
    const float4* t4 = (const float4*)(target + base);
    for (int j4 = threadIdx.x; j4 < YN / 4; j4 += 256) {
        float4 v = t4[j4];
        int c0 = 4 * j4;
        if (v.x != 0.0f) { ws_pos[row] = c0;     ws_ps[row] = input[base + c0];     }
        if (v.y != 0.0f) { ws_pos[row] = c0 + 1; ws_ps[row] = input[base + c0 + 1]; }
        if (v.z != 0.0f) { ws_pos[row] = c0 + 2; ws_ps[row] = input[base + c0 + 2]; }
        if (v.w != 0.0f) { ws_pos[row] = c0 + 3; ws_ps[row] = input[base + c0 + 3]; }
    }
}

// ---------------- Kernel 2: per-row first violator + rank + loss ------------
__global__ __launch_bounds__(256) void warp_main_kernel(
    const float* __restrict__ input,
    const int* __restrict__ ws_pos, const float* __restrict__ ws_ps,
    const int* __restrict__ mt_ptr, float* __restrict__ row_loss)
{
    const int row = blockIdx.x;
    const int tid = threadIdx.x;
    const int pos = ws_pos[row];
    const float ps = ws_ps[row];
    const uint32_t maxt = (uint32_t)mt_ptr[0];
    const size_t base = (size_t)row * YN;
    const uint32_t base32 = (uint32_t)base;   // B*Y = 51.2M < 2^32
    const float* rowp = input + base;

    __shared__ uint64_t smin[256];
    __shared__ uint32_t ssum[256];

    // Phase A: min (u,col) over violators: margin (1+s)-ps >= 0, col != pos
    uint64_t mk = ~0ull;
    const float4* rowp4 = (const float4*)rowp;
    for (int j4 = tid; j4 < YN / 4; j4 += 256) {
        float4 v = rowp4[j4];
        float sv[4] = {v.x, v.y, v.z, v.w};
        int c0 = 4 * j4;
#pragma unroll
        for (int k = 0; k < 4; ++k) {
            int col = c0 + k;
            uint32_t bits = tf_bits(base32 + (uint32_t)col);
            uint64_t key = sort_key(bits, col);
            float m = (1.0f + sv[k]) - ps;
            if ((m >= 0.0f) && (col != pos) && (key < mk)) mk = key;
        }
    }
    smin[tid] = mk;
    __syncthreads();
    for (int s = 128; s > 0; s >>= 1) {
        if (tid < s) { uint64_t o = smin[tid + s]; if (o < smin[tid]) smin[tid] = o; }
        __syncthreads();
    }
    const uint64_t kstar = smin[0];

    if (kstar == ~0ull) {
        if (tid == 0) row_loss[row] = 0.0f;
        return;
    }

    // Phase B: rank = #negatives with (u,col) < kstar  (pure recompute, no loads)
    uint32_t cnt = 0;
    for (int col = tid; col < YN; col += 256) {
        uint32_t bits = tf_bits(base32 + (uint32_t)col);
        uint64_t key = sort_key(bits, col);
        cnt += ((col != pos) && (key < kstar)) ? 1u : 0u;
    }
    ssum[tid] = cnt;
    __syncthreads();
    for (int s = 128; s > 0; s >>= 1) {
        if (tid < s) ssum[tid] += ssum[tid + s];
        __syncthreads();
    }

    if (tid == 0) {
        uint32_t rank = ssum[0];          // first violating trial index t
        float loss = 0.0f;
        if (rank < maxt) {
            int cstar = (int)(kstar & 0xffffffffu);
            float ns = rowp[cstar];
            float nt = (float)(rank + 1u);
            float L = logf(floorf(49999.0f / nt));
            loss = L * ((1.0f - ps) + ns);
        }
        row_loss[row] = loss;
    }
}

// ---------------- Kernel 3: reduce 1024 row losses -> out[0] ----------------
__global__ __launch_bounds__(256) void reduce_kernel(
    const float* __restrict__ row_loss, float* __restrict__ out)
{
    __shared__ float s[256];
    int tid = threadIdx.x;
    float acc = 0.0f;
    for (int i = tid; i < BN; i += 256) acc += row_loss[i];
    s[tid] = acc;
    __syncthreads();
    for (int st = 128; st > 0; st >>= 1) {
        if (tid < st) s[tid] += s[tid + st];
        __syncthreads();
    }
    if (tid == 0) out[0] = s[0];
}

extern "C" void kernel_launch(void* const* d_in, const int* in_sizes, int n_in,
                              void* d_out, int out_size, void* d_ws, size_t ws_size,
                              hipStream_t stream) {
    const float* input  = (const float*)d_in[0];
    const float* target = (const float*)d_in[1];
    const int*   mt     = (const int*)d_in[2];
    float* out = (float*)d_out;

    // workspace layout: [0,BN) int pos | [BN,2BN) float pos_score | [2BN,3BN) float row_loss
    int*   ws_pos  = (int*)d_ws;
    float* ws_ps   = (float*)d_ws + BN;
    float* ws_loss = (float*)d_ws + 2 * BN;

    find_pos_kernel<<<BN, 256, 0, stream>>>(target, input, ws_pos, ws_ps);
    warp_main_kernel<<<BN, 256, 0, stream>>>(input, ws_pos, ws_ps, mt, ws_loss);
    reduce_kernel<<<1, 256, 0, stream>>>(ws_loss, out);
}

// Round 2
// 471.824 us; speedup vs baseline: 1.2445x; 1.2445x over previous
//
#include <hip/hip_runtime.h>
#include <stdint.h>

// WARP loss, B=1024, Y=50000. inputs: input_ f32[B*Y], target f32[B*Y],
// max_num_trials i32[1]; output f32[1] = sum of per-row losses.
//
// Exact-RNG reduction (validated absmax 0.0 in R1): per row, first violator in
// the random permutation == violator with min (u_bits>>9, col); num_trials-1 ==
// rank == #{negatives with key < kstar}. R2: rank via a tiny LDS list of all
// keys < T (E[|list|]~12) gathered during phase A -> kills the 2nd threefry pass.
#define BN 1024
#define YN 50000
#define LIST_CAP 256
#define KEYHI_T (1u << 11)   // threshold on (bits>>9): 1/4096 of keyspace

// ---------------- Threefry-2x32, key (0,42), counter (0, i) -----------------
#define TF_ROUND(r) { x0 += x1; x1 = (x1 << (r)) | (x1 >> (32 - (r))); x1 ^= x0; }

__device__ __forceinline__ uint32_t tf_bits(uint32_t ctr) {
    const uint32_t ks0 = 0u;
    const uint32_t ks1 = 42u;
    const uint32_t ks2 = 0x1BD11BDAu ^ 0u ^ 42u;
    uint32_t x0 = ks0;        // hi counter (0) + ks0
    uint32_t x1 = ctr + ks1;  // lo counter + ks1
    TF_ROUND(13) TF_ROUND(15) TF_ROUND(26) TF_ROUND(6)
    x0 += ks1; x1 += ks2 + 1u;
    TF_ROUND(17) TF_ROUND(29) TF_ROUND(16) TF_ROUND(24)
    x0 += ks2; x1 += ks0 + 2u;
    TF_ROUND(13) TF_ROUND(15) TF_ROUND(26) TF_ROUND(6)
    x0 += ks0; x1 += ks1 + 3u;
    TF_ROUND(17) TF_ROUND(29) TF_ROUND(16) TF_ROUND(24)
    x0 += ks1; x1 += ks2 + 4u;
    TF_ROUND(13) TF_ROUND(15) TF_ROUND(26) TF_ROUND(6)
    x0 += ks2; x1 += ks0 + 5u;
    return x0 ^ x1;
}

// ---------------- Fused kernel: one block per row ---------------------------
__global__ __launch_bounds__(256) void warp_fused_kernel(
    const float* __restrict__ input, const float* __restrict__ target,
    const int* __restrict__ mt_ptr, float* __restrict__ row_loss)
{
    const int row = blockIdx.x;
    const int tid = threadIdx.x;
    const size_t base = (size_t)row * YN;
    const uint32_t base32 = (uint32_t)base;     // B*Y = 51.2M < 2^32
    const float* rowp = input + base;

    __shared__ volatile int s_pos;
    __shared__ float s_ps;
    __shared__ uint64_t smin[256];
    __shared__ uint64_t s_list[LIST_CAP];
    __shared__ int s_nlist;
    __shared__ uint32_t s_cnt[256];

    if (tid == 0) { s_pos = -1; s_nlist = 0; }
    __syncthreads();

    // Phase 0: find the one-hot position; early-exit once any thread found it.
    const float4* t4 = (const float4*)(target + base);
    for (int j4 = tid; j4 < YN / 4; j4 += 256) {
        if (s_pos >= 0) break;                   // benign racy read; exact value
        float4 v = t4[j4];                       // is fixed at the barrier below
        int c0 = 4 * j4;
        if (v.x != 0.0f) { s_ps = rowp[c0];     s_pos = c0;     }
        if (v.y != 0.0f) { s_ps = rowp[c0 + 1]; s_pos = c0 + 1; }
        if (v.z != 0.0f) { s_ps = rowp[c0 + 2]; s_pos = c0 + 2; }
        if (v.w != 0.0f) { s_ps = rowp[c0 + 3]; s_pos = c0 + 3; }
    }
    __syncthreads();
    const int pos = s_pos;
    const float ps = s_ps;

    // Phase A: min key over violators + gather all keys < T into s_list.
    uint64_t mk = ~0ull;
    const float4* r4 = (const float4*)rowp;
    for (int j4 = tid; j4 < YN / 4; j4 += 256) {
        float4 v = r4[j4];
        float sv[4] = {v.x, v.y, v.z, v.w};
        int c0 = 4 * j4;
#pragma unroll
        for (int k = 0; k < 4; ++k) {
            int col = c0 + k;
            uint32_t bits = tf_bits(base32 + (uint32_t)col);
            uint32_t kh = bits >> 9;
            uint64_t key = ((uint64_t)kh << 32) | (uint32_t)col;
            if (kh < KEYHI_T) {                  // E ~12 hits per row
                int idx = atomicAdd(&s_nlist, 1);
                if (idx < LIST_CAP) s_list[idx] = key;
            }
            float m = (1.0f + sv[k]) - ps;
            if ((m >= 0.0f) && (col != pos) && (key < mk)) mk = key;
        }
    }
    smin[tid] = mk;
    __syncthreads();
    for (int s = 128; s > 0; s >>= 1) {
        if (tid < s) { uint64_t o = smin[tid + s]; if (o < smin[tid]) smin[tid] = o; }
        __syncthreads();
    }
    const uint64_t kstar = smin[0];

    if (kstar == ~0ull) {                        // no violator at all
        if (tid == 0) row_loss[row] = 0.0f;
        return;
    }

    const uint32_t maxt = (uint32_t)mt_ptr[0];
    const int nlist = s_nlist;
    const bool fast = (nlist <= LIST_CAP) && ((uint32_t)(kstar >> 32) < KEYHI_T);

    uint32_t rank;
    if (fast) {
        // rank = #{list entries: key < kstar, col != pos}; list covers all
        // keys < T >= all keys < kstar. Tiny: let thread 0 do it.
        if (tid != 0) return;
        uint32_t r = 0;
        for (int i = 0; i < nlist; ++i) {
            uint64_t e = s_list[i];
            if (e < kstar && (int)(uint32_t)(e & 0xffffffffu) != pos) r++;
        }
        rank = r;
    } else {
        // Rare (~1e-4 of rows): full recount pass.
        uint32_t c = 0;
        for (int col = tid; col < YN; col += 256) {
            uint32_t bits = tf_bits(base32 + (uint32_t)col);
            uint64_t key = ((uint64_t)(bits >> 9) << 32) | (uint32_t)col;
            if ((key < kstar) && (col != pos)) c++;
        }
        s_cnt[tid] = c;
        __syncthreads();
        for (int s = 128; s > 0; s >>= 1) {
            if (tid < s) s_cnt[tid] += s_cnt[tid + s];
            __syncthreads();
        }
        if (tid != 0) return;
        rank = s_cnt[0];
    }

    // thread 0 only
    float loss = 0.0f;
    if (rank < maxt) {
        uint32_t cstar = (uint32_t)(kstar & 0xffffffffu);
        float ns = rowp[cstar];
        float nt = (float)(rank + 1u);
        loss = logf(floorf(49999.0f / nt)) * ((1.0f - ps) + ns);
    }
    row_loss[row] = loss;
}

// ---------------- reduce 1024 row losses -> out[0] --------------------------
__global__ __launch_bounds__(256) void reduce_kernel(
    const float* __restrict__ row_loss, float* __restrict__ out)
{
    __shared__ float s[256];
    int tid = threadIdx.x;
    float acc = 0.0f;
    for (int i = tid; i < BN; i += 256) acc += row_loss[i];
    s[tid] = acc;
    __syncthreads();
    for (int st = 128; st > 0; st >>= 1) {
        if (tid < st) s[tid] += s[tid + st];
        __syncthreads();
    }
    if (tid == 0) out[0] = s[0];
}

extern "C" void kernel_launch(void* const* d_in, const int* in_sizes, int n_in,
                              void* d_out, int out_size, void* d_ws, size_t ws_size,
                              hipStream_t stream) {
    const float* input  = (const float*)d_in[0];
    const float* target = (const float*)d_in[1];
    const int*   mt     = (const int*)d_in[2];
    float* out = (float*)d_out;

    float* ws_loss = (float*)d_ws;   // BN floats

    warp_fused_kernel<<<BN, 256, 0, stream>>>(input, target, mt, ws_loss);
    reduce_kernel<<<1, 256, 0, stream>>>(ws_loss, out);
}

// Round 3
// 456.986 us; speedup vs baseline: 1.2849x; 1.0325x over previous
//
#include <hip/hip_runtime.h>
#include <stdint.h>

// WARP loss, B=1024, Y=50000. inputs: input_ f32[B*Y], target f32[B*Y],
// max_num_trials i32[1]; output f32[1] = sum of per-row losses.
//
// Exact-RNG reduction (absmax 0.0 in R1/R2): first violator in the random
// permutation == violator with min (u_bits>>9, col); num_trials-1 == rank ==
// #{cols != pos with key < kstar}.
// R3: keys are input-independent -> gen kernel pushes all keys < T=2^14 into
// per-row candidate lists (E~98/row) with NO input reads; resolve kernel does
// margin tests only on candidates; rare rows with no violating candidate take
// a full-scan fallback.
#define BN 1024
#define YN 50000
#define SEGS 8              // threefry segments per row
#define SEGLEN 6250         // YN / SEGS
#define CAP 192             // per-row candidate capacity (Poisson(98), P(>192)~1e-17)
#define KEYHI_T (1u << 14)  // threshold on (bits>>9)

// ---------------- Threefry-2x32, key (0,42), counter (0, i) -----------------
#define TF_ROUND(r) { x0 += x1; x1 = (x1 << (r)) | (x1 >> (32 - (r))); x1 ^= x0; }

__device__ __forceinline__ uint32_t tf_bits(uint32_t ctr) {
    const uint32_t ks0 = 0u;
    const uint32_t ks1 = 42u;
    const uint32_t ks2 = 0x1BD11BDAu ^ 0u ^ 42u;
    uint32_t x0 = ks0;
    uint32_t x1 = ctr + ks1;
    TF_ROUND(13) TF_ROUND(15) TF_ROUND(26) TF_ROUND(6)
    x0 += ks1; x1 += ks2 + 1u;
    TF_ROUND(17) TF_ROUND(29) TF_ROUND(16) TF_ROUND(24)
    x0 += ks2; x1 += ks0 + 2u;
    TF_ROUND(13) TF_ROUND(15) TF_ROUND(26) TF_ROUND(6)
    x0 += ks0; x1 += ks1 + 3u;
    TF_ROUND(17) TF_ROUND(29) TF_ROUND(16) TF_ROUND(24)
    x0 += ks1; x1 += ks2 + 4u;
    TF_ROUND(13) TF_ROUND(15) TF_ROUND(26) TF_ROUND(6)
    x0 += ks2; x1 += ks0 + 5u;
    return x0 ^ x1;
}

// ws layout (floats/ints, 4B units):
//   cnt[BN]      @ 0
//   flag[BN]     @ BN
//   pos[BN]      @ 2*BN
//   ps[BN]       @ 3*BN
//   row_loss[BN] @ 4*BN
//   cand[BN*CAP] @ 5*BN
struct WS {
    uint32_t* cnt; int* flag; int* pos; float* ps; float* row_loss; uint32_t* cand;
};
static inline WS ws_layout(void* d_ws) {
    uint32_t* p = (uint32_t*)d_ws;
    WS w;
    w.cnt = p; w.flag = (int*)(p + BN); w.pos = (int*)(p + 2 * BN);
    w.ps = (float*)(p + 3 * BN); w.row_loss = (float*)(p + 4 * BN);
    w.cand = p + 5 * BN;
    return w;
}

// ---------------- Kernel 1: candidate gen (threefry) + target scan ----------
// blocks [0, BN): target scan, one row each (placed first so the memory-bound
// role starts immediately and hides under the VALU-bound threefry blocks).
// blocks [BN, BN + BN*SEGS): threefry over one row segment each.
__global__ __launch_bounds__(256) void gen_kernel(
    const float* __restrict__ input, const float* __restrict__ target,
    uint32_t* __restrict__ cnt, uint32_t* __restrict__ cand,
    int* __restrict__ pos_out, float* __restrict__ ps_out)
{
    const int tid = threadIdx.x;
    if (blockIdx.x < BN) {
        // ---- target scan role ----
        const int row = blockIdx.x;
        const size_t base = (size_t)row * YN;
        __shared__ volatile int s_pos;
        if (tid == 0) s_pos = -1;
        __syncthreads();
        const float4* t4 = (const float4*)(target + base);
        for (int j4 = tid; j4 < YN / 4; j4 += 256) {
            if (s_pos >= 0) break;               // benign racy early-exit
            float4 v = t4[j4];
            int c0 = 4 * j4;
            if (v.x != 0.0f) s_pos = c0;
            if (v.y != 0.0f) s_pos = c0 + 1;
            if (v.z != 0.0f) s_pos = c0 + 2;
            if (v.w != 0.0f) s_pos = c0 + 3;
        }
        __syncthreads();
        if (tid == 0) {
            int p = s_pos;
            pos_out[row] = p;
            ps_out[row] = input[base + p];
        }
        return;
    }
    // ---- threefry role ----
    const int b = blockIdx.x - BN;
    const int row = b >> 3;                      // b / SEGS
    const int seg = b & 7;                       // b % SEGS
    const uint32_t base32 = (uint32_t)row * YN;
    const int start = seg * SEGLEN;
    const int end = start + SEGLEN;
    uint32_t* mycnt = cnt + row;
    uint32_t* mycand = cand + row * CAP;
    for (int col = start + tid; col < end; col += 256) {
        uint32_t bits = tf_bits(base32 + (uint32_t)col);
        uint32_t kh = bits >> 9;
        if (kh < KEYHI_T) {
            uint32_t idx = atomicAdd(mycnt, 1u);
            if (idx < CAP) mycand[idx] = (kh << 17) | (uint32_t)col;
        }
    }
}

// ---------------- Kernel 2: resolve per row from candidate list -------------
// one wave per row; grid = BN*64 threads = (BN/4) blocks of 256.
__global__ __launch_bounds__(256) void resolve_kernel(
    const float* __restrict__ input, const uint32_t* __restrict__ cnt,
    const uint32_t* __restrict__ cand, const int* __restrict__ pos_,
    const float* __restrict__ ps_, const int* __restrict__ mt_ptr,
    float* __restrict__ row_loss, int* __restrict__ flag)
{
    const int gtid = blockIdx.x * 256 + threadIdx.x;
    const int row = gtid >> 6;
    const int lane = gtid & 63;
    const uint32_t n = cnt[row];
    if (n > CAP) { if (lane == 0) flag[row] = 1; return; }
    const int pos = pos_[row];
    const float ps = ps_[row];
    const uint32_t* cl = cand + row * CAP;
    const float* rowp = input + (size_t)row * YN;

    // min packed key among violating candidates
    uint32_t mk = 0xFFFFFFFFu;
    for (uint32_t i = lane; i < n; i += 64) {
        uint32_t e = cl[i];
        int col = (int)(e & 0x1FFFFu);
        if (col == pos) continue;
        float s = rowp[col];
        if ((1.0f + s) - ps >= 0.0f) mk = (e < mk) ? e : mk;
    }
    for (int off = 32; off > 0; off >>= 1) {
        uint32_t o = (uint32_t)__shfl_xor((int)mk, off, 64);
        mk = (o < mk) ? o : mk;
    }
    if (mk == 0xFFFFFFFFu) {           // no violating candidate: fallback row
        if (lane == 0) flag[row] = 1;  // (covers the true no-violator case too)
        return;
    }
    // rank = #{candidates: key < mk, col != pos}  (all keys < kstar are < T,
    // hence in the list)
    uint32_t c = 0;
    for (uint32_t i = lane; i < n; i += 64) {
        uint32_t e = cl[i];
        int col = (int)(e & 0x1FFFFu);
        c += ((e < mk) && (col != pos)) ? 1u : 0u;
    }
    for (int off = 32; off > 0; off >>= 1) c += (uint32_t)__shfl_xor((int)c, off, 64);
    if (lane == 0) {
        uint32_t rank = c;
        float loss = 0.0f;
        if (rank < (uint32_t)mt_ptr[0]) {
            int cstar = (int)(mk & 0x1FFFFu);
            float ns = rowp[cstar];
            float nt = (float)(rank + 1u);
            loss = logf(floorf(49999.0f / nt)) * ((1.0f - ps) + ns);
        }
        row_loss[row] = loss;
    }
}

// ---------------- Kernel 3: fallback full scan for flagged rows (rare) ------
__global__ __launch_bounds__(256) void fallback_kernel(
    const float* __restrict__ input, const int* __restrict__ flag,
    const int* __restrict__ pos_, const float* __restrict__ ps_,
    const int* __restrict__ mt_ptr, float* __restrict__ row_loss)
{
    const int row = blockIdx.x;
    if (!flag[row]) return;
    const int tid = threadIdx.x;
    const int pos = pos_[row];
    const float ps = ps_[row];
    const uint32_t base32 = (uint32_t)row * YN;
    const float* rowp = input + (size_t)row * YN;

    __shared__ uint64_t smin[256];
    __shared__ uint32_t ssum[256];

    // full min over violators, 40-bit packed key (keyhi23 << 17 | col)
    uint64_t mk = ~0ull;
    for (int col = tid; col < YN; col += 256) {
        uint32_t bits = tf_bits(base32 + (uint32_t)col);
        uint64_t key = ((uint64_t)(bits >> 9) << 17) | (uint32_t)col;
        float m = (1.0f + rowp[col]) - ps;
        if ((m >= 0.0f) && (col != pos) && (key < mk)) mk = key;
    }
    smin[tid] = mk;
    __syncthreads();
    for (int s = 128; s > 0; s >>= 1) {
        if (tid < s) { uint64_t o = smin[tid + s]; if (o < smin[tid]) smin[tid] = o; }
        __syncthreads();
    }
    const uint64_t kstar = smin[0];
    if (kstar == ~0ull) {
        if (tid == 0) row_loss[row] = 0.0f;
        return;
    }
    // rank
    uint32_t c = 0;
    for (int col = tid; col < YN; col += 256) {
        uint32_t bits = tf_bits(base32 + (uint32_t)col);
        uint64_t key = ((uint64_t)(bits >> 9) << 17) | (uint32_t)col;
        c += ((key < kstar) && (col != pos)) ? 1u : 0u;
    }
    ssum[tid] = c;
    __syncthreads();
    for (int s = 128; s > 0; s >>= 1) {
        if (tid < s) ssum[tid] += ssum[tid + s];
        __syncthreads();
    }
    if (tid == 0) {
        uint32_t rank = ssum[0];
        float loss = 0.0f;
        if (rank < (uint32_t)mt_ptr[0]) {
            int cstar = (int)(kstar & 0x1FFFFull);
            float ns = rowp[cstar];
            float nt = (float)(rank + 1u);
            loss = logf(floorf(49999.0f / nt)) * ((1.0f - ps) + ns);
        }
        row_loss[row] = loss;
    }
}

// ---------------- Kernel 4: reduce row losses -> out[0] ---------------------
__global__ __launch_bounds__(256) void reduce_kernel(
    const float* __restrict__ row_loss, float* __restrict__ out)
{
    __shared__ float s[256];
    int tid = threadIdx.x;
    float acc = 0.0f;
    for (int i = tid; i < BN; i += 256) acc += row_loss[i];
    s[tid] = acc;
    __syncthreads();
    for (int st = 128; st > 0; st >>= 1) {
        if (tid < st) s[tid] += s[tid + st];
        __syncthreads();
    }
    if (tid == 0) out[0] = s[0];
}

extern "C" void kernel_launch(void* const* d_in, const int* in_sizes, int n_in,
                              void* d_out, int out_size, void* d_ws, size_t ws_size,
                              hipStream_t stream) {
    const float* input  = (const float*)d_in[0];
    const float* target = (const float*)d_in[1];
    const int*   mt     = (const int*)d_in[2];
    float* out = (float*)d_out;
    WS w = ws_layout(d_ws);

    // zero cnt + flag (harness poisons ws with 0xAA before every launch)
    hipMemsetAsync(d_ws, 0, 2 * BN * sizeof(uint32_t), stream);

    gen_kernel<<<BN + BN * SEGS, 256, 0, stream>>>(
        input, target, w.cnt, w.cand, w.pos, w.ps);
    resolve_kernel<<<BN / 4, 256, 0, stream>>>(
        input, w.cnt, w.cand, w.pos, w.ps, mt, w.row_loss, w.flag);
    fallback_kernel<<<BN, 256, 0, stream>>>(
        input, w.flag, w.pos, w.ps, mt, w.row_loss);
    reduce_kernel<<<1, 256, 0, stream>>>(w.row_loss, out);
}